// Round 1
// baseline (319.166 us; speedup 1.0000x reference)
//
#include <hip/hip_runtime.h>

// out[0, z, r, c, ch] = in[0, z_idx[z], row_idx[r], col_idx[c], 0]
// in : (1,128,128,128,32) f32 ; out : (1,64,64,64,32) f32
// One float4 store per lane -> 8 lanes per (z,r,c) cell (32 channels).

__global__ __launch_bounds__(256) void ds3d_kernel(
    const float* __restrict__ in,
    const int* __restrict__ zi,
    const int* __restrict__ ri,
    const int* __restrict__ ci,
    float4* __restrict__ out)
{
    const int t    = blockIdx.x * blockDim.x + threadIdx.x;  // 0 .. 64^3*8-1
    const int cell = t >> 3;          // which (z,r,c) cell
    const int c    = cell & 63;
    const int r    = (cell >> 6) & 63;
    const int z    = cell >> 12;

    const int iz = zi[z];
    const int ir = ri[r];
    const int ic = ci[c];

    // channel-0 element of gathered voxel: ((iz*128 + ir)*128 + ic)*32
    const float v = in[(((iz << 7) + ir) << 7 | ic) << 5];

    out[t] = make_float4(v, v, v, v);  // out float index = cell*32 + (t&7)*4
}

extern "C" void kernel_launch(void* const* d_in, const int* in_sizes, int n_in,
                              void* d_out, int out_size, void* d_ws, size_t ws_size,
                              hipStream_t stream)
{
    const float* in = (const float*)d_in[0];
    const int*   zi = (const int*)d_in[1];
    const int*   ri = (const int*)d_in[2];
    const int*   ci = (const int*)d_in[3];
    float4* out = (float4*)d_out;

    // total float4 stores = 64*64*64*32/4 = 2,097,152
    const int total  = 64 * 64 * 64 * 8;
    const int block  = 256;
    const int grid   = total / block;   // 8192
    ds3d_kernel<<<grid, block, 0, stream>>>(in, zi, ri, ci, out);
}